// Round 1
// baseline (14903.616 us; speedup 1.0000x reference)
//
#include <hip/hip_runtime.h>

#define BATCH_N 16384
#define PLANE 262144          // 512*512 elements per weight matrix
typedef unsigned short ushort_t;
typedef __attribute__((ext_vector_type(4))) float f32x4;
typedef __attribute__((ext_vector_type(8))) short s16x8;
typedef __attribute__((ext_vector_type(4))) unsigned short u16x4;

// Cheap truncating hi/lo bf16 split: v ~= hi + lo to ~2^-16 relative.
__device__ inline void split_bf(float f, ushort_t& h, ushort_t& l) {
    unsigned u = __float_as_uint(f);
    h = (ushort_t)(u >> 16);
    float fh = __uint_as_float(u & 0xFFFF0000u);
    float r = f - fh;
    l = (ushort_t)(__float_as_uint(r) >> 16);
}

// ---------------------------------------------------------------------------
// Weight conversion: fp32 -> hi/lo bf16 planes. One float4 per thread.
// ---------------------------------------------------------------------------
__global__ __launch_bounds__(256) void convert_w_k(
    const float* __restrict__ src, ushort_t* __restrict__ hi,
    ushort_t* __restrict__ lo, int n4)
{
    const int i = blockIdx.x * 256 + threadIdx.x;
    if (i >= n4) return;
    const f32x4 v = ((const f32x4*)src)[i];
    ushort_t h[4], l[4];
#pragma unroll
    for (int u = 0; u < 4; ++u) split_bf(v[u], h[u], l[u]);
    *(u16x4*)&hi[(size_t)i * 4] = (u16x4){h[0], h[1], h[2], h[3]};
    *(u16x4*)&lo[(size_t)i * 4] = (u16x4){l[0], l[1], l[2], l[3]};
}

// ---------------------------------------------------------------------------
// Split-bf16 MFMA GEMM, tile 128x128, BK=32, 4 waves of 64x64.
// out[m][n] = sum_k A[m][k] * W[n][k]  (+ bias / logits epilogue)
// A fp32 (converted to hi/lo during staging); W pre-split bf16 planes.
// EPI=0: out = acc + bias[n]          (grid.z = 1)
// EPI=1: logits[b][p] += sum_n (acc + bk[p][n]) * q[b][n]   (grid.z = 9)
// MFMA 16x16x32 layouts (verified):
//   A/B frag: row/col = lane&15, k = (lane>>4)*8 + j
//   C/D:      col = lane&15, row = (lane>>4)*4 + reg
//
// LDS: combined hi|lo rows of 64 ushorts (=128B): [0..31]=hi, [32..63]=lo,
// XOR-swizzled in 16B (8-ushort) units by (row&7) on BOTH write and read.
// Rationale: ds_read_b128 with 128B row stride puts all 64 lanes on the
// same bank-group set; the XOR spreads each 8-lane phase across all 8
// 4-bank groups -> conflict-free (verified pattern, G4/attn ladder).
// ---------------------------------------------------------------------------
template <int EPI>
__global__ __launch_bounds__(256, 5) void mfma_gemm_k(
    const float* __restrict__ A, int lda, int aoff,
    const ushort_t* __restrict__ Wh, const ushort_t* __restrict__ Wl,
    const float* __restrict__ bias, float* __restrict__ outp,
    const float* __restrict__ q, float* __restrict__ logits)
{
    __shared__ __align__(16) ushort_t Ac[128 * 64];
    __shared__ __align__(16) ushort_t Bc[128 * 64];

    const int t = threadIdx.x;
    const int lane = t & 63, wave = t >> 6;
    const int wm = (wave >> 1) * 64, wn = (wave & 1) * 64;
    const int quad = lane >> 4, l15 = lane & 15;
    const size_t b0 = (size_t)blockIdx.x * 128;
    const int n0 = blockIdx.y * 128;
    int p = 0;
    if (EPI == 1) {
        p = blockIdx.z;
        Wh += (size_t)PLANE * p;
        Wl += (size_t)PLANE * p;
        aoff += p * 512;
    }

    // read-side swizzled within-row offsets (ushort units); row&7 == l15&7
    // for all fragment rows (wm, wn, i*16 are multiples of 8).
    const int xr = (l15 & 7) << 3;
    const int offh = (quad * 8) ^ xr;          // hi chunk
    const int offl = (32 + quad * 8) ^ xr;     // lo chunk

    f32x4 acc[4][4] = {};

    for (int k0 = 0; k0 < 512; k0 += 32) {
        // ---- global prefetch into registers
        f32x4 av[4];
        s16x8 bhv[2], blv[2];
#pragma unroll
        for (int u = 0; u < 4; ++u) {
            const int f = t + 256 * u, row = f >> 3, c = f & 7;
            av[u] = *(const f32x4*)&A[(b0 + row) * lda + aoff + k0 + c * 4];
        }
#pragma unroll
        for (int u = 0; u < 2; ++u) {
            const int f = t + 256 * u, row = f >> 2, c = f & 3;
            bhv[u] = *(const s16x8*)&Wh[(size_t)(n0 + row) * 512 + k0 + c * 8];
            blv[u] = *(const s16x8*)&Wl[(size_t)(n0 + row) * 512 + k0 + c * 8];
        }
        __syncthreads();
        // ---- stage to LDS (A converted to hi/lo), swizzled addresses
#pragma unroll
        for (int u = 0; u < 4; ++u) {
            const int f = t + 256 * u, row = f >> 3, c = f & 7;
            const int xw = (row & 7) << 3;
            ushort_t h[4], l[4];
#pragma unroll
            for (int e = 0; e < 4; ++e) split_bf(av[u][e], h[e], l[e]);
            *(u16x4*)&Ac[row * 64 + ((c * 4) ^ xw)]      = (u16x4){h[0], h[1], h[2], h[3]};
            *(u16x4*)&Ac[row * 64 + ((32 + c * 4) ^ xw)] = (u16x4){l[0], l[1], l[2], l[3]};
        }
#pragma unroll
        for (int u = 0; u < 2; ++u) {
            const int f = t + 256 * u, row = f >> 2, c = f & 3;
            const int xw = (row & 7) << 3;
            *(s16x8*)&Bc[row * 64 + ((c * 8) ^ xw)]      = bhv[u];
            *(s16x8*)&Bc[row * 64 + ((32 + c * 8) ^ xw)] = blv[u];
        }
        __syncthreads();
        // ---- MFMA: 16 tiles x 3 split-products
        s16x8 ah[4], alo[4];
#pragma unroll
        for (int i = 0; i < 4; ++i) {
            ah[i]  = *(const s16x8*)&Ac[(wm + i * 16 + l15) * 64 + offh];
            alo[i] = *(const s16x8*)&Ac[(wm + i * 16 + l15) * 64 + offl];
        }
#pragma unroll
        for (int j = 0; j < 4; ++j) {
            const s16x8 bh = *(const s16x8*)&Bc[(wn + j * 16 + l15) * 64 + offh];
            const s16x8 bl = *(const s16x8*)&Bc[(wn + j * 16 + l15) * 64 + offl];
#pragma unroll
            for (int i = 0; i < 4; ++i) {
                acc[i][j] = __builtin_amdgcn_mfma_f32_16x16x32_bf16(ah[i], bh, acc[i][j], 0, 0, 0);
                acc[i][j] = __builtin_amdgcn_mfma_f32_16x16x32_bf16(ah[i], bl, acc[i][j], 0, 0, 0);
                acc[i][j] = __builtin_amdgcn_mfma_f32_16x16x32_bf16(alo[i], bh, acc[i][j], 0, 0, 0);
            }
        }
    }

    if (EPI == 0) {
#pragma unroll
        for (int i = 0; i < 4; ++i) {
            const int gm0 = (int)b0 + wm + i * 16 + quad * 4;
#pragma unroll
            for (int j = 0; j < 4; ++j) {
                const int gn = n0 + wn + j * 16 + l15;
                const float bv = bias[gn];
#pragma unroll
                for (int r = 0; r < 4; ++r)
                    outp[(size_t)(gm0 + r) * 512 + gn] = acc[i][j][r] + bv;
            }
        }
    } else {
        float rp[4][4] = {};
#pragma unroll
        for (int i = 0; i < 4; ++i) {
            const int gm0 = (int)b0 + wm + i * 16 + quad * 4;
#pragma unroll
            for (int j = 0; j < 4; ++j) {
                const int gn = n0 + wn + j * 16 + l15;
                const float bv = bias[(size_t)p * 512 + gn];
#pragma unroll
                for (int r = 0; r < 4; ++r)
                    rp[i][r] += (acc[i][j][r] + bv) * q[(size_t)(gm0 + r) * 512 + gn];
            }
        }
#pragma unroll
        for (int m = 1; m < 16; m <<= 1)
#pragma unroll
            for (int i = 0; i < 4; ++i)
#pragma unroll
                for (int r = 0; r < 4; ++r)
                    rp[i][r] += __shfl_xor(rp[i][r], m, 64);
        if (l15 == 0) {
#pragma unroll
            for (int i = 0; i < 4; ++i) {
                const int gm0 = (int)b0 + wm + i * 16 + quad * 4;
#pragma unroll
                for (int r = 0; r < 4; ++r)
                    atomicAdd(&logits[(size_t)(gm0 + r) * 9 + p], rp[i][r]);
            }
        }
    }
}

// ---------------------------------------------------------------------------
// softmax over 9 logits; cent = sum_p a_p x[b,p,:];
// mode 0: out = l2norm(cent)
// mode 1: out = l2norm(cent + x[b,8,:])   (final)
// ---------------------------------------------------------------------------
__global__ __launch_bounds__(256) void softmax_cent_k(
    const float* __restrict__ x, const float* __restrict__ logits,
    float* __restrict__ outp, int mode)
{
    const int lane = threadIdx.x & 63;
    const size_t b = (size_t)blockIdx.x * 4 + (threadIdx.x >> 6);
    float lg[9], m = -1e30f;
#pragma unroll
    for (int p = 0; p < 9; ++p) { lg[p] = logits[b * 9 + p]; m = fmaxf(m, lg[p]); }
    float s = 0.f;
#pragma unroll
    for (int p = 0; p < 9; ++p) { lg[p] = __expf(lg[p] - m); s += lg[p]; }
    const float inv = 1.0f / s;
    f32x4 c[2];
    float ssq = 0.f;
#pragma unroll
    for (int v = 0; v < 2; ++v) {
        f32x4 a = {0.f, 0.f, 0.f, 0.f};
#pragma unroll
        for (int p = 0; p < 9; ++p) {
            const f32x4 xv = ((const f32x4*)&x[(b * 9 + p) * 512])[v * 64 + lane];
            a += lg[p] * xv;
        }
        a *= inv;
        if (mode) a += ((const f32x4*)&x[(b * 9 + 8) * 512])[v * 64 + lane];
        c[v] = a;
        ssq += a[0]*a[0] + a[1]*a[1] + a[2]*a[2] + a[3]*a[3];
    }
#pragma unroll
    for (int off = 32; off > 0; off >>= 1) ssq += __shfl_xor(ssq, off, 64);
    const float invn = 1.0f / fmaxf(sqrtf(ssq), 1e-12f);
#pragma unroll
    for (int v = 0; v < 2; ++v)
        ((f32x4*)&outp[b * 512])[v * 64 + lane] = c[v] * invn;
}

// ---------------------------------------------------------------------------
// dst_row = l2norm(dst_row + src_row); dst stride in floats, src stride 512.
// ---------------------------------------------------------------------------
__global__ __launch_bounds__(256) void resid_norm_k(
    float* __restrict__ dst, int dstride, const float* __restrict__ src)
{
    const int lane = threadIdx.x & 63;
    const size_t b = (size_t)blockIdx.x * 4 + (threadIdx.x >> 6);
    f32x4* d4 = (f32x4*)&dst[b * (size_t)dstride];
    const f32x4* s4 = (const f32x4*)&src[b * 512];
    f32x4 a[2];
    float ssq = 0.f;
#pragma unroll
    for (int v = 0; v < 2; ++v) {
        a[v] = d4[v * 64 + lane] + s4[v * 64 + lane];
        ssq += a[v][0]*a[v][0] + a[v][1]*a[v][1] + a[v][2]*a[v][2] + a[v][3]*a[v][3];
    }
#pragma unroll
    for (int off = 32; off > 0; off >>= 1) ssq += __shfl_xor(ssq, off, 64);
    const float invn = 1.0f / fmaxf(sqrtf(ssq), 1e-12f);
#pragma unroll
    for (int v = 0; v < 2; ++v) d4[v * 64 + lane] = a[v] * invn;
}

// ---------------------------------------------------------------------------
extern "C" void kernel_launch(void* const* d_in, const int* in_sizes, int n_in,
                              void* d_out, int out_size, void* d_ws, size_t ws_size,
                              hipStream_t stream) {
    (void)in_sizes; (void)n_in; (void)out_size; (void)ws_size;
    float* x = (float*)d_in[0];   // mutated in place; harness restores per launch
    const float* Wq  = (const float*)d_in[1];
    const float* bq  = (const float*)d_in[2];
    const float* Wk  = (const float*)d_in[3];
    const float* bk  = (const float*)d_in[4];
    const float* Wfw = (const float*)d_in[5];
    const float* bfw = (const float*)d_in[6];
    const float* Wfc = (const float*)d_in[7];
    const float* bfc = (const float*)d_in[8];
    const float* Wqf = (const float*)d_in[9];
    const float* bqf = (const float*)d_in[10];
    const float* Wkf = (const float*)d_in[11];
    const float* bkf = (const float*)d_in[12];
    float* out = (float*)d_out;

    // ws layout: [hi planes | lo planes | q | cent(=tmp) | y | logits]
    ushort_t* whi = (ushort_t*)d_ws;
    ushort_t* wlo = whi + (size_t)67 * PLANE;
    float* fbuf   = (float*)(wlo + (size_t)67 * PLANE);
    float* q      = fbuf;                          // B*512
    float* cent   = q    + (size_t)BATCH_N * 512;  // B*512 (reused as window tmp)
    float* y      = cent + (size_t)BATCH_N * 512;  // B*512
    float* logits = y    + (size_t)BATCH_N * 512;  // B*9
    float* tmp    = cent;

    // plane offsets (units of PLANE): Wq 0(3), Wk 3(27), Wfw 30(24), Wfc 54(3),
    // Wqf 57(1), Wkf 58(9)
    const size_t OWq = 0, OWk = 3, OWfw = 30, OWfc = 54, OWqf = 57, OWkf = 58;

    // ---- one-time (per launch) weight split
    struct { const float* s; size_t off; int cnt; } cv[6] = {
        {Wq, OWq, 3}, {Wk, OWk, 27}, {Wfw, OWfw, 24},
        {Wfc, OWfc, 3}, {Wqf, OWqf, 1}, {Wkf, OWkf, 9}};
    for (int i = 0; i < 6; ++i) {
        const int n4 = cv[i].cnt * PLANE / 4;
        convert_w_k<<<(n4 + 255) / 256, 256, 0, stream>>>(
            cv[i].s, whi + cv[i].off * PLANE, wlo + cv[i].off * PLANE, n4);
    }

    const dim3 gemm_grid(BATCH_N / 128, 4);
    const dim3 log_grid(BATCH_N / 128, 4, 9);
    const int ew_grid = BATCH_N / 4;

    for (int l = 0; l < 3; ++l) {
        // q = x[:,8,:] @ Wq^T + bq
        mfma_gemm_k<0><<<gemm_grid, 256, 0, stream>>>(
            x, 9 * 512, 8 * 512,
            whi + (OWq + l) * PLANE, wlo + (OWq + l) * PLANE,
            bq + l * 512, q, nullptr, nullptr);
        // logits
        hipMemsetAsync(logits, 0, (size_t)BATCH_N * 9 * sizeof(float), stream);
        mfma_gemm_k<1><<<log_grid, 256, 0, stream>>>(
            x, 9 * 512, 0,
            whi + (OWk + (size_t)l * 9) * PLANE, wlo + (OWk + (size_t)l * 9) * PLANE,
            bk + (size_t)l * 9 * 512, nullptr, q, logits);
        // cent = l2norm(softmax-weighted sum)
        softmax_cent_k<<<ew_grid, 256, 0, stream>>>(x, logits, cent, 0);
        // y = cent @ Wfc^T + bfc
        mfma_gemm_k<0><<<gemm_grid, 256, 0, stream>>>(
            cent, 512, 0,
            whi + (OWfc + l) * PLANE, wlo + (OWfc + l) * PLANE,
            bfc + l * 512, y, nullptr, nullptr);
        // x[:,8,:] = l2norm(x[:,8,:] + y)
        resid_norm_k<<<ew_grid, 256, 0, stream>>>(x + 8 * 512, 9 * 512, y);
        // window: per p, tmp = x[:,p,:]@Wfw[p]^T + bfw[p]; x[:,p,:]=l2norm(x+tmp)
        for (int p = 0; p < 8; ++p) {
            mfma_gemm_k<0><<<gemm_grid, 256, 0, stream>>>(
                x, 9 * 512, p * 512,
                whi + (OWfw + (size_t)l * 8 + p) * PLANE,
                wlo + (OWfw + (size_t)l * 8 + p) * PLANE,
                bfw + ((size_t)l * 8 + p) * 512, tmp, nullptr, nullptr);
            resid_norm_k<<<ew_grid, 256, 0, stream>>>(x + p * 512, 9 * 512, tmp);
        }
    }
    // final attention -> out
    mfma_gemm_k<0><<<gemm_grid, 256, 0, stream>>>(
        x, 9 * 512, 8 * 512, whi + OWqf * PLANE, wlo + OWqf * PLANE,
        bqf, q, nullptr, nullptr);
    hipMemsetAsync(logits, 0, (size_t)BATCH_N * 9 * sizeof(float), stream);
    mfma_gemm_k<1><<<log_grid, 256, 0, stream>>>(
        x, 9 * 512, 0, whi + OWkf * PLANE, wlo + OWkf * PLANE,
        bkf, nullptr, q, logits);
    softmax_cent_k<<<ew_grid, 256, 0, stream>>>(x, logits, out, 1);
}

// Round 3
// 3194.551 us; speedup vs baseline: 4.6653x; 4.6653x over previous
//
#include <hip/hip_runtime.h>

#define BATCH_N 16384
#define PPLANE 524288         // 512 rows * 1024 ushorts per packed weight plane
typedef unsigned short ushort_t;
typedef __attribute__((ext_vector_type(4))) float f32x4;
typedef __attribute__((ext_vector_type(8))) short s16x8;

// Cheap truncating hi/lo bf16 split: v ~= hi + lo to ~2^-16 relative.
__device__ inline void split_bf(float f, ushort_t& h, ushort_t& l) {
    unsigned u = __float_as_uint(f);
    h = (ushort_t)(u >> 16);
    float fh = __uint_as_float(u & 0xFFFF0000u);
    float r = f - fh;
    l = (ushort_t)(__float_as_uint(r) >> 16);
}

// ---------------------------------------------------------------------------
// Weight packing: fp32 row (512) -> packed swizzled hi|lo row (1024 ushorts).
// Row layout: 16 k-chunks (32 k each) x 8 slots x 8 ushorts (16B).
// Slot s of chunk kc holds: c = s ^ (row&7); c<4 -> hi[k=kc*32+c*8 ..+8),
// else lo[k=kc*32+(c-4)*8 ..+8). This IS the LDS image the GEMM wants, so
// GEMM-side B staging is a linear copy. One wave per row; lane handles 8 k.
// ---------------------------------------------------------------------------
__global__ __launch_bounds__(256) void pack_w_k(
    const float* __restrict__ src, ushort_t* __restrict__ dst, int nrows)
{
    const int lane = threadIdx.x & 63;
    const int row = blockIdx.x * 4 + (threadIdx.x >> 6);
    if (row >= nrows) return;
    const int r = row & 7;
    const int kc = lane >> 2, c = lane & 3;
    const float* s = src + (size_t)row * 512 + kc * 32 + c * 8;
    const f32x4 v0 = *(const f32x4*)s;
    const f32x4 v1 = *(const f32x4*)(s + 4);
    s16x8 hv, lv;
    ushort_t h, l;
#pragma unroll
    for (int e = 0; e < 4; ++e) { split_bf(v0[e], h, l); hv[e] = (short)h; lv[e] = (short)l; }
#pragma unroll
    for (int e = 0; e < 4; ++e) { split_bf(v1[e], h, l); hv[4 + e] = (short)h; lv[4 + e] = (short)l; }
    ushort_t* base = dst + (size_t)row * 1024 + kc * 64;
    *(s16x8*)&base[(c ^ r) * 8]       = hv;
    *(s16x8*)&base[((4 + c) ^ r) * 8] = lv;
}

// ---------------------------------------------------------------------------
// Split-bf16 MFMA GEMM, tile 128x128, BK=32, 4 waves of 64x64.
// out[m][n] = sum_k A[m][k] * W[n][k]  (+ bias / logits epilogue)
// A fp32 (split to packed image during staging); W pre-packed (pack_w_k).
// EPI=0: out = acc + bias[n]          (grid.z = 1)
// EPI=1: logits[b][p] += sum_n (acc + bk[p][n]) * q[b][n]   (grid.z = 9)
// MFMA 16x16x32 layouts (verified):
//   A/B frag: row/col = lane&15, k = (lane>>4)*8 + j
//   C/D:      col = lane&15, row = (lane>>4)*4 + reg
// LDS image per row (64 ushorts = 128B): slot s holds chunk s^(row&7)
// (chunks 0-3 = hi, 4-7 = lo). Reads XOR by (l15&7) -> each 8-lane phase of
// ds_read_b128 covers all 32 banks: conflict-free. A writes are b128 at XOR'd
// slots (lanes 0-7 = rows 0-7, all 8 groups): conflict-free. B writes are
// linear consecutive 16B (source pre-swizzled by pack_w_k): conflict-free.
// NOTE __launch_bounds__(256,3): unified VGPR+AGPR footprint ~136; bound 4+
// caps the budget below that and spills acc to scratch (round-1 disaster:
// WRITE_SIZE 36MB->4.6GB, 5x slowdown). Do not raise.
// ---------------------------------------------------------------------------
template <int EPI>
__global__ __launch_bounds__(256, 3) void mfma_gemm_k(
    const float* __restrict__ A, int lda, int aoff,
    const ushort_t* __restrict__ Wpk,
    const float* __restrict__ bias, float* __restrict__ outp,
    const float* __restrict__ q, float* __restrict__ logits)
{
    __shared__ __align__(16) ushort_t As[128 * 64];
    __shared__ __align__(16) ushort_t Bs[128 * 64];

    const int t = threadIdx.x;
    const int lane = t & 63, wave = t >> 6;
    const int wm = (wave >> 1) * 64, wn = (wave & 1) * 64;
    const int quad = lane >> 4, l15 = lane & 15;
    const size_t b0 = (size_t)blockIdx.x * 128;
    const int n0 = blockIdx.y * 128;
    int p = 0;
    if (EPI == 1) {
        p = blockIdx.z;
        Wpk += (size_t)PPLANE * p;
        aoff += p * 512;
    }

    // ---- A staging geometry: row = t&127 (fixed); chunks c = (t>>7) + 2u
    const int arow = t & 127;
    const int rr = arow & 7;
    const float* aptr = A + (b0 + arow) * (size_t)lda + aoff + (t >> 7) * 8;
    ushort_t* awr_hi[2];
    ushort_t* awr_lo[2];
#pragma unroll
    for (int u = 0; u < 2; ++u) {
        const int c = (t >> 7) + 2 * u;
        awr_hi[u] = &As[arow * 64 + ((c ^ rr) * 8)];
        awr_lo[u] = &As[arow * 64 + (((4 + c) ^ rr) * 8)];
    }

    // read-side swizzled within-row offsets (ushort units); row&7 == l15&7.
    const int xr = (l15 & 7) << 3;
    const int offh = (quad * 8) ^ xr;          // hi chunk
    const int offl = (32 + quad * 8) ^ xr;     // lo chunk

    f32x4 acc[4][4] = {};

    for (int kc = 0; kc < 16; ++kc) {
        // ---- global prefetch into registers (overlaps prev MFMA tail)
        f32x4 av[4];
#pragma unroll
        for (int u = 0; u < 2; ++u) {
            av[2 * u]     = *(const f32x4*)(aptr + kc * 32 + u * 16);
            av[2 * u + 1] = *(const f32x4*)(aptr + kc * 32 + u * 16 + 4);
        }
        s16x8 bv[4];
#pragma unroll
        for (int u = 0; u < 4; ++u) {
            const int f = t + 256 * u;                       // 0..1023
            bv[u] = *(const s16x8*)&Wpk[(size_t)(n0 + (f >> 3)) * 1024
                                        + kc * 64 + (f & 7) * 8];
        }
        __syncthreads();    // prev-iter LDS reads done
        // ---- A: split to hi/lo, b128 writes at swizzled slots
#pragma unroll
        for (int u = 0; u < 2; ++u) {
            s16x8 hv, lv;
            ushort_t h, l;
#pragma unroll
            for (int e = 0; e < 4; ++e) {
                split_bf(av[2 * u][e], h, l); hv[e] = (short)h; lv[e] = (short)l;
            }
#pragma unroll
            for (int e = 0; e < 4; ++e) {
                split_bf(av[2 * u + 1][e], h, l); hv[4 + e] = (short)h; lv[4 + e] = (short)l;
            }
            *(s16x8*)awr_hi[u] = hv;
            *(s16x8*)awr_lo[u] = lv;
        }
        // ---- B: linear b128 writes of the pre-swizzled image
#pragma unroll
        for (int u = 0; u < 4; ++u) {
            const int f = t + 256 * u;
            *(s16x8*)&Bs[f * 8] = bv[u];
        }
        __syncthreads();
        // ---- MFMA: 16 tiles x 3 split-products
        s16x8 ah[4], alo[4];
#pragma unroll
        for (int i = 0; i < 4; ++i) {
            ah[i]  = *(const s16x8*)&As[(wm + i * 16 + l15) * 64 + offh];
            alo[i] = *(const s16x8*)&As[(wm + i * 16 + l15) * 64 + offl];
        }
#pragma unroll
        for (int j = 0; j < 4; ++j) {
            const s16x8 bh = *(const s16x8*)&Bs[(wn + j * 16 + l15) * 64 + offh];
            const s16x8 bl = *(const s16x8*)&Bs[(wn + j * 16 + l15) * 64 + offl];
#pragma unroll
            for (int i = 0; i < 4; ++i) {
                acc[i][j] = __builtin_amdgcn_mfma_f32_16x16x32_bf16(ah[i], bh, acc[i][j], 0, 0, 0);
                acc[i][j] = __builtin_amdgcn_mfma_f32_16x16x32_bf16(ah[i], bl, acc[i][j], 0, 0, 0);
                acc[i][j] = __builtin_amdgcn_mfma_f32_16x16x32_bf16(alo[i], bh, acc[i][j], 0, 0, 0);
            }
        }
    }

    if (EPI == 0) {
#pragma unroll
        for (int i = 0; i < 4; ++i) {
            const int gm0 = (int)b0 + wm + i * 16 + quad * 4;
#pragma unroll
            for (int j = 0; j < 4; ++j) {
                const int gn = n0 + wn + j * 16 + l15;
                const float bv = bias[gn];
#pragma unroll
                for (int r = 0; r < 4; ++r)
                    outp[(size_t)(gm0 + r) * 512 + gn] = acc[i][j][r] + bv;
            }
        }
    } else {
        float rp[4][4] = {};
#pragma unroll
        for (int i = 0; i < 4; ++i) {
            const int gm0 = (int)b0 + wm + i * 16 + quad * 4;
#pragma unroll
            for (int j = 0; j < 4; ++j) {
                const int gn = n0 + wn + j * 16 + l15;
                const float bv = bias[(size_t)p * 512 + gn];
#pragma unroll
                for (int r = 0; r < 4; ++r)
                    rp[i][r] += (acc[i][j][r] + bv) * q[(size_t)(gm0 + r) * 512 + gn];
            }
        }
#pragma unroll
        for (int m = 1; m < 16; m <<= 1)
#pragma unroll
            for (int i = 0; i < 4; ++i)
#pragma unroll
                for (int r = 0; r < 4; ++r)
                    rp[i][r] += __shfl_xor(rp[i][r], m, 64);
        if (l15 == 0) {
#pragma unroll
            for (int i = 0; i < 4; ++i) {
                const int gm0 = (int)b0 + wm + i * 16 + quad * 4;
#pragma unroll
                for (int r = 0; r < 4; ++r)
                    atomicAdd(&logits[(size_t)(gm0 + r) * 9 + p], rp[i][r]);
            }
        }
    }
}

// ---------------------------------------------------------------------------
// softmax over 9 logits; cent = sum_p a_p x[b,p,:];
// mode 0: out = l2norm(cent)
// mode 1: out = l2norm(cent + x[b,8,:])   (final)
// ---------------------------------------------------------------------------
__global__ __launch_bounds__(256) void softmax_cent_k(
    const float* __restrict__ x, const float* __restrict__ logits,
    float* __restrict__ outp, int mode)
{
    const int lane = threadIdx.x & 63;
    const size_t b = (size_t)blockIdx.x * 4 + (threadIdx.x >> 6);
    float lg[9], m = -1e30f;
#pragma unroll
    for (int p = 0; p < 9; ++p) { lg[p] = logits[b * 9 + p]; m = fmaxf(m, lg[p]); }
    float s = 0.f;
#pragma unroll
    for (int p = 0; p < 9; ++p) { lg[p] = __expf(lg[p] - m); s += lg[p]; }
    const float inv = 1.0f / s;
    f32x4 c[2];
    float ssq = 0.f;
#pragma unroll
    for (int v = 0; v < 2; ++v) {
        f32x4 a = {0.f, 0.f, 0.f, 0.f};
#pragma unroll
        for (int p = 0; p < 9; ++p) {
            const f32x4 xv = ((const f32x4*)&x[(b * 9 + p) * 512])[v * 64 + lane];
            a += lg[p] * xv;
        }
        a *= inv;
        if (mode) a += ((const f32x4*)&x[(b * 9 + 8) * 512])[v * 64 + lane];
        c[v] = a;
        ssq += a[0]*a[0] + a[1]*a[1] + a[2]*a[2] + a[3]*a[3];
    }
#pragma unroll
    for (int off = 32; off > 0; off >>= 1) ssq += __shfl_xor(ssq, off, 64);
    const float invn = 1.0f / fmaxf(sqrtf(ssq), 1e-12f);
#pragma unroll
    for (int v = 0; v < 2; ++v)
        ((f32x4*)&outp[b * 512])[v * 64 + lane] = c[v] * invn;
}

// ---------------------------------------------------------------------------
// dst_row = l2norm(dst_row + src_row); dst stride in floats, src stride 512.
// ---------------------------------------------------------------------------
__global__ __launch_bounds__(256) void resid_norm_k(
    float* __restrict__ dst, int dstride, const float* __restrict__ src)
{
    const int lane = threadIdx.x & 63;
    const size_t b = (size_t)blockIdx.x * 4 + (threadIdx.x >> 6);
    f32x4* d4 = (f32x4*)&dst[b * (size_t)dstride];
    const f32x4* s4 = (const f32x4*)&src[b * 512];
    f32x4 a[2];
    float ssq = 0.f;
#pragma unroll
    for (int v = 0; v < 2; ++v) {
        a[v] = d4[v * 64 + lane] + s4[v * 64 + lane];
        ssq += a[v][0]*a[v][0] + a[v][1]*a[v][1] + a[v][2]*a[v][2] + a[v][3]*a[v][3];
    }
#pragma unroll
    for (int off = 32; off > 0; off >>= 1) ssq += __shfl_xor(ssq, off, 64);
    const float invn = 1.0f / fmaxf(sqrtf(ssq), 1e-12f);
#pragma unroll
    for (int v = 0; v < 2; ++v) d4[v * 64 + lane] = a[v] * invn;
}

// ---------------------------------------------------------------------------
extern "C" void kernel_launch(void* const* d_in, const int* in_sizes, int n_in,
                              void* d_out, int out_size, void* d_ws, size_t ws_size,
                              hipStream_t stream) {
    (void)in_sizes; (void)n_in; (void)out_size; (void)ws_size;
    float* x = (float*)d_in[0];   // mutated in place; harness restores per launch
    const float* Wq  = (const float*)d_in[1];
    const float* bq  = (const float*)d_in[2];
    const float* Wk  = (const float*)d_in[3];
    const float* bk  = (const float*)d_in[4];
    const float* Wfw = (const float*)d_in[5];
    const float* bfw = (const float*)d_in[6];
    const float* Wfc = (const float*)d_in[7];
    const float* bfc = (const float*)d_in[8];
    const float* Wqf = (const float*)d_in[9];
    const float* bqf = (const float*)d_in[10];
    const float* Wkf = (const float*)d_in[11];
    const float* bkf = (const float*)d_in[12];
    float* out = (float*)d_out;

    // ws layout: [packed weight planes | q | cent(=tmp) | y | logits]
    ushort_t* wpk = (ushort_t*)d_ws;
    float* fbuf   = (float*)(wpk + (size_t)67 * PPLANE);
    float* q      = fbuf;                          // B*512
    float* cent   = q    + (size_t)BATCH_N * 512;  // B*512 (reused as window tmp)
    float* y      = cent + (size_t)BATCH_N * 512;  // B*512
    float* logits = y    + (size_t)BATCH_N * 512;  // B*9
    float* tmp    = cent;

    // plane offsets (units of PPLANE): Wq 0(3), Wk 3(27), Wfw 30(24), Wfc 54(3),
    // Wqf 57(1), Wkf 58(9)
    const size_t OWq = 0, OWk = 3, OWfw = 30, OWfc = 54, OWqf = 57, OWkf = 58;

    // ---- one-time (per launch) weight packing into swizzled LDS image
    struct { const float* s; size_t off; int cnt; } cv[6] = {
        {Wq, OWq, 3}, {Wk, OWk, 27}, {Wfw, OWfw, 24},
        {Wfc, OWfc, 3}, {Wqf, OWqf, 1}, {Wkf, OWkf, 9}};
    for (int i = 0; i < 6; ++i) {
        const int nrows = cv[i].cnt * 512;
        pack_w_k<<<nrows / 4, 256, 0, stream>>>(
            cv[i].s, wpk + cv[i].off * PPLANE, nrows);
    }

    const dim3 gemm_grid(BATCH_N / 128, 4);
    const dim3 log_grid(BATCH_N / 128, 4, 9);
    const int ew_grid = BATCH_N / 4;

    for (int l = 0; l < 3; ++l) {
        // q = x[:,8,:] @ Wq^T + bq
        mfma_gemm_k<0><<<gemm_grid, 256, 0, stream>>>(
            x, 9 * 512, 8 * 512,
            wpk + (OWq + l) * PPLANE,
            bq + l * 512, q, nullptr, nullptr);
        // logits
        hipMemsetAsync(logits, 0, (size_t)BATCH_N * 9 * sizeof(float), stream);
        mfma_gemm_k<1><<<log_grid, 256, 0, stream>>>(
            x, 9 * 512, 0,
            wpk + (OWk + (size_t)l * 9) * PPLANE,
            bk + (size_t)l * 9 * 512, nullptr, q, logits);
        // cent = l2norm(softmax-weighted sum)
        softmax_cent_k<<<ew_grid, 256, 0, stream>>>(x, logits, cent, 0);
        // y = cent @ Wfc^T + bfc
        mfma_gemm_k<0><<<gemm_grid, 256, 0, stream>>>(
            cent, 512, 0,
            wpk + (OWfc + l) * PPLANE,
            bfc + l * 512, y, nullptr, nullptr);
        // x[:,8,:] = l2norm(x[:,8,:] + y)
        resid_norm_k<<<ew_grid, 256, 0, stream>>>(x + 8 * 512, 9 * 512, y);
        // window: per p, tmp = x[:,p,:]@Wfw[p]^T + bfw[p]; x[:,p,:]=l2norm(x+tmp)
        for (int p = 0; p < 8; ++p) {
            mfma_gemm_k<0><<<gemm_grid, 256, 0, stream>>>(
                x, 9 * 512, p * 512,
                wpk + (OWfw + (size_t)l * 8 + p) * PPLANE,
                bfw + ((size_t)l * 8 + p) * 512, tmp, nullptr, nullptr);
            resid_norm_k<<<ew_grid, 256, 0, stream>>>(x + p * 512, 9 * 512, tmp);
        }
    }
    // final attention -> out
    mfma_gemm_k<0><<<gemm_grid, 256, 0, stream>>>(
        x, 9 * 512, 8 * 512, wpk + OWqf * PPLANE,
        bqf, q, nullptr, nullptr);
    hipMemsetAsync(logits, 0, (size_t)BATCH_N * 9 * sizeof(float), stream);
    mfma_gemm_k<1><<<log_grid, 256, 0, stream>>>(
        x, 9 * 512, 0, wpk + OWkf * PPLANE,
        bkf, nullptr, q, logits);
    softmax_cent_k<<<ew_grid, 256, 0, stream>>>(x, logits, out, 1);
}